// Round 1
// baseline (36.403 us; speedup 1.0000x reference)
//
#include <hip/hip_runtime.h>
#include <math.h>

// ChamferLossSplitPID: B=512 batches, N=M=256 points, D=4, PIDs 0..3.
// Output: d_out[0] = sum_b(sum_{p=1..3} loss_p) / B ; d_out[1+b] = (sum_{out_pid==0} |y|)/max(c0,1)/B

constexpr int BATCH = 512;
constexpr int NP    = 256;   // points per cloud
constexpr float INF2 = 1e30f; // sentinel for masked squared distances

__device__ __forceinline__ float dist2_f4(const float4 a, const float4 b) {
    float dx = a.x - b.x;
    float dy = a.y - b.y;
    float dz = a.z - b.z;
    float dw = a.w - b.w;
    return dx * dx + dy * dy + dz * dz + dw * dw;
}

__global__ __launch_bounds__(256) void chamfer_pid_kernel(
    const float* __restrict__ target,   // [B, NP, 4]
    const float* __restrict__ reco,     // [B, NP, 4]
    const int*   __restrict__ in_pid,   // [B, NP]
    const int*   __restrict__ out_pid,  // [B, NP]
    float* __restrict__ out,            // [1 + B]
    float* __restrict__ ws)             // [B] per-batch nonzero loss
{
    const int b = blockIdx.x;
    const int i = threadIdx.x;

    __shared__ float4 sx[NP];
    __shared__ float4 sy[NP];
    __shared__ int    spin[NP];
    __shared__ int    spout[NP];

    // per-pid accumulators
    __shared__ float s_sxy[4];   // sum over x of min-dist (pid 1..3)
    __shared__ float s_syx[4];   // sum over y of min-dist (pid 1..3)
    __shared__ float s_snx[4];   // sum |x| per pid
    __shared__ float s_sny[4];   // sum |y| per pid (pid 0 used too)
    __shared__ int   s_cx[4];
    __shared__ int   s_cy[4];

    if (i < 4) {
        s_sxy[i] = 0.0f; s_syx[i] = 0.0f;
        s_snx[i] = 0.0f; s_sny[i] = 0.0f;
        s_cx[i] = 0;     s_cy[i] = 0;
    }

    const float4* tgt = reinterpret_cast<const float4*>(target) + (size_t)b * NP;
    const float4* rec = reinterpret_cast<const float4*>(reco)   + (size_t)b * NP;

    const float4 xp = tgt[i];
    const float4 yp = rec[i];
    const int pn = in_pid[(size_t)b * NP + i];
    const int pm = out_pid[(size_t)b * NP + i];

    sx[i] = xp; sy[i] = yp;
    spin[i] = pn; spout[i] = pm;
    __syncthreads();

    // role 1: target point i -> min over reco points with out_pid == pn
    float minx = INF2;
    // role 2: reco point i -> min over target points with in_pid == pm
    float miny = INF2;

    #pragma unroll 8
    for (int j = 0; j < NP; ++j) {
        // wave-uniform LDS addresses -> broadcast reads, no conflicts
        const float4 yj = sy[j];
        const int    pj = spout[j];
        float dx2 = dist2_f4(xp, yj);
        minx = fminf(minx, (pj == pn) ? dx2 : INF2);

        const float4 xj = sx[j];
        const int    qj = spin[j];
        float dy2 = dist2_f4(xj, yp);
        miny = fminf(miny, (qj == pm) ? dy2 : INF2);
    }

    const float normx = sqrtf(xp.x * xp.x + xp.y * xp.y + xp.z * xp.z + xp.w * xp.w);
    const float normy = sqrtf(yp.x * yp.x + yp.y * yp.y + yp.z * yp.z + yp.w * yp.w);

    // accumulate per-pid sums (LDS atomics; cheap vs the 512-iter loop)
    if (pn >= 1) {   // pids 1..3 participate in the nonzero loss (x side)
        atomicAdd(&s_sxy[pn], sqrtf(minx));   // sqrt(min d2) == min(sqrt d)
        atomicAdd(&s_snx[pn], normx);
        atomicAdd(&s_cx[pn], 1);
    }
    atomicAdd(&s_sny[pm], normy);             // pid 0 norm-sum needed for output 1
    atomicAdd(&s_cy[pm], 1);
    if (pm >= 1) {
        atomicAdd(&s_syx[pm], sqrtf(miny));
    }
    __syncthreads();

    if (i == 0) {
        float nonzero = 0.0f;
        #pragma unroll
        for (int p = 1; p < 4; ++p) {
            const int cx = s_cx[p];
            const int cy = s_cy[p];
            const float n_in  = (float)(cx > 1 ? cx : 1);
            const float n_out = (float)(cy > 1 ? cy : 1);
            float loss;
            if (cy == 0) {
                loss = s_snx[p] / n_in;
            } else if (cx == 0) {
                loss = s_sny[p] / n_out;
            } else {
                loss = 0.5f * (s_sxy[p] / n_out + s_syx[p] / n_in);
            }
            nonzero += loss;
        }
        ws[b] = nonzero;

        const int c0 = s_cy[0];
        const float c0f = (float)(c0 > 1 ? c0 : 1);
        out[1 + b] = (s_sny[0] / c0f) / (float)BATCH;
    }
}

__global__ __launch_bounds__(256) void chamfer_reduce_kernel(
    const float* __restrict__ ws,  // [B]
    float* __restrict__ out)       // out[0]
{
    __shared__ float red[256];
    const int i = threadIdx.x;
    red[i] = ws[i] + ws[i + 256];
    __syncthreads();
    #pragma unroll
    for (int s = 128; s > 0; s >>= 1) {
        if (i < s) red[i] += red[i + s];
        __syncthreads();
    }
    if (i == 0) {
        out[0] = red[0] / (float)BATCH;
    }
}

extern "C" void kernel_launch(void* const* d_in, const int* in_sizes, int n_in,
                              void* d_out, int out_size, void* d_ws, size_t ws_size,
                              hipStream_t stream) {
    const float* target  = (const float*)d_in[0];
    const float* reco    = (const float*)d_in[1];
    const int*   in_pid  = (const int*)d_in[2];
    const int*   out_pid = (const int*)d_in[3];
    float* out = (float*)d_out;
    float* ws  = (float*)d_ws;

    chamfer_pid_kernel<<<BATCH, 256, 0, stream>>>(target, reco, in_pid, out_pid, out, ws);
    chamfer_reduce_kernel<<<1, 256, 0, stream>>>(ws, out);
}

// Round 6
// 22.195 us; speedup vs baseline: 1.6401x; 1.6401x over previous
//
#include <hip/hip_runtime.h>
#include <math.h>

// ChamferLossSplitPID: B=512 batches, N=M=256 points, D=4, PIDs 0..3.
// d_out[0] = sum_b(sum_{p=1..3} loss_p) / B ; d_out[1+b] = (sum_{out_pid==0} |y|)/max(c0,1)/B
//
// R2: partition both point clouds by pid in LDS (atomic-slot scatter; segment
// order is irrelevant for a min), then each point only scans its matching pid
// segment (~64 pts avg) instead of all 256 with a mask. Removes the per-pair
// pid compare too.

constexpr int BATCH = 512;
constexpr int NP    = 256;
constexpr float INF2 = 1e30f;

__device__ __forceinline__ float dist2_f4(const float4 a, const float4 b) {
    float dx = a.x - b.x;
    float dy = a.y - b.y;
    float dz = a.z - b.z;
    float dw = a.w - b.w;
    return dx * dx + dy * dy + dz * dz + dw * dw;
}

__global__ __launch_bounds__(256) void chamfer_pid_kernel(
    const float* __restrict__ target,   // [B, NP, 4]
    const float* __restrict__ reco,     // [B, NP, 4]
    const int*   __restrict__ in_pid,   // [B, NP]
    const int*   __restrict__ out_pid,  // [B, NP]
    float* __restrict__ out,            // [1 + B]
    float* __restrict__ ws)             // [B] per-batch nonzero loss
{
    const int b = blockIdx.x;
    const int i = threadIdx.x;

    __shared__ float4 sxs[NP];          // x points grouped by pid
    __shared__ float4 sys[NP];          // y points grouped by pid
    __shared__ int   s_cx[4], s_cy[4];  // per-pid counts (atomic slots)
    __shared__ int   s_offx[4], s_offy[4];
    __shared__ float s_sxy[4], s_syx[4], s_snx[4], s_sny[4];

    if (i < 4) {
        s_cx[i] = 0;     s_cy[i] = 0;
        s_sxy[i] = 0.f;  s_syx[i] = 0.f;
        s_snx[i] = 0.f;  s_sny[i] = 0.f;
    }
    __syncthreads();

    const float4 xp = reinterpret_cast<const float4*>(target)[(size_t)b * NP + i];
    const float4 yp = reinterpret_cast<const float4*>(reco)  [(size_t)b * NP + i];
    const int pn = in_pid [(size_t)b * NP + i];
    const int pm = out_pid[(size_t)b * NP + i];

    // count + grab scatter slot in one atomic
    const int slotx = atomicAdd(&s_cx[pn], 1);
    const int sloty = atomicAdd(&s_cy[pm], 1);
    __syncthreads();

    if (i == 0) {
        int ox = 0, oy = 0;
        #pragma unroll
        for (int p = 0; p < 4; ++p) {
            s_offx[p] = ox; ox += s_cx[p];
            s_offy[p] = oy; oy += s_cy[p];
        }
    }
    __syncthreads();

    sxs[s_offx[pn] + slotx] = xp;
    sys[s_offy[pm] + sloty] = yp;
    __syncthreads();

    // role 1: x-point i (pid pn>=1) -> min d2 over y segment of pid pn
    const int basey = s_offy[pn];
    const int cnty  = s_cy[pn];
    float minx = INF2;
    if (pn >= 1) {
        for (int j = 0; j < cnty; ++j) {
            minx = fminf(minx, dist2_f4(xp, sys[basey + j]));
        }
    }

    // role 2: y-point i (pid pm>=1) -> min d2 over x segment of pid pm
    const int basex = s_offx[pm];
    const int cntx  = s_cx[pm];
    float miny = INF2;
    if (pm >= 1) {
        for (int j = 0; j < cntx; ++j) {
            miny = fminf(miny, dist2_f4(sxs[basex + j], yp));
        }
    }

    const float normx = sqrtf(xp.x * xp.x + xp.y * xp.y + xp.z * xp.z + xp.w * xp.w);
    const float normy = sqrtf(yp.x * yp.x + yp.y * yp.y + yp.z * yp.z + yp.w * yp.w);

    if (pn >= 1) {
        atomicAdd(&s_snx[pn], normx);
        if (cnty > 0) atomicAdd(&s_sxy[pn], sqrtf(minx));  // sqrt(min d2) == min dist
    }
    atomicAdd(&s_sny[pm], normy);
    if (pm >= 1 && cntx > 0) atomicAdd(&s_syx[pm], sqrtf(miny));
    __syncthreads();

    if (i == 0) {
        float nonzero = 0.0f;
        #pragma unroll
        for (int p = 1; p < 4; ++p) {
            const int cx = s_cx[p];
            const int cy = s_cy[p];
            const float n_in  = (float)(cx > 1 ? cx : 1);
            const float n_out = (float)(cy > 1 ? cy : 1);
            float loss;
            if (cy == 0) {
                loss = s_snx[p] / n_in;
            } else if (cx == 0) {
                loss = s_sny[p] / n_out;
            } else {
                loss = 0.5f * (s_sxy[p] / n_out + s_syx[p] / n_in);
            }
            nonzero += loss;
        }
        ws[b] = nonzero;

        const int c0 = s_cy[0];
        const float c0f = (float)(c0 > 1 ? c0 : 1);
        out[1 + b] = (s_sny[0] / c0f) / (float)BATCH;
    }
}

__global__ __launch_bounds__(256) void chamfer_reduce_kernel(
    const float* __restrict__ ws,  // [B]
    float* __restrict__ out)       // out[0]
{
    __shared__ float red[256];
    const int i = threadIdx.x;
    red[i] = ws[i] + ws[i + 256];
    __syncthreads();
    #pragma unroll
    for (int s = 128; s > 0; s >>= 1) {
        if (i < s) red[i] += red[i + s];
        __syncthreads();
    }
    if (i == 0) {
        out[0] = red[0] / (float)BATCH;
    }
}

extern "C" void kernel_launch(void* const* d_in, const int* in_sizes, int n_in,
                              void* d_out, int out_size, void* d_ws, size_t ws_size,
                              hipStream_t stream) {
    const float* target  = (const float*)d_in[0];
    const float* reco    = (const float*)d_in[1];
    const int*   in_pid  = (const int*)d_in[2];
    const int*   out_pid = (const int*)d_in[3];
    float* out = (float*)d_out;
    float* ws  = (float*)d_ws;

    chamfer_pid_kernel<<<BATCH, 256, 0, stream>>>(target, reco, in_pid, out_pid, out, ws);
    chamfer_reduce_kernel<<<1, 256, 0, stream>>>(ws, out);
}